// Round 1
// baseline (248.713 us; speedup 1.0000x reference)
//
#include <hip/hip_runtime.h>

#define CC 100000
#define DD 512

#define S_SCALE 30.0f
#define COS_M_C 0.8775825618903728f
#define SIN_M_C 0.479425538604203f
#define THRESH_C (-0.8775825618903728f)
#define MM_C 0.2397127693021015f

typedef __attribute__((ext_vector_type(8))) short short8;
typedef __attribute__((ext_vector_type(4))) float f32x4;

static __device__ __forceinline__ unsigned short f2bf(float x) {
  unsigned int u = __float_as_uint(x);
  unsigned int r = (u + 0x7fffu + ((u >> 16) & 1u)) >> 16;
  return (unsigned short)r;
}

// ---------------------------------------------------------------------------
// Kernel 1: per embedding row i (one wave per row):
//  - L2-normalize row, convert to bf16, store into ws_A in the k-tiled +
//    XOR-swizzled layout the GEMM's linear global_load_lds staging expects:
//      ws_A byte offset = (k>>5)*32768 + m*64 + ((2*(k&31)) ^ ((m&3)<<4))
//  - compute target logit = clip(dot(e_n, w_n)), cos_theta_m, final_target
// ---------------------------------------------------------------------------
__global__ __launch_bounds__(64) void k1_prep(
    const float* __restrict__ emb, const float* __restrict__ kern,
    const int* __restrict__ label, unsigned short* __restrict__ wsA,
    float* __restrict__ ws_target, float* __restrict__ ws_ctm,
    float* __restrict__ ws_ft) {
  const int i = blockIdx.x;
  const int l = threadIdx.x;  // 0..63, owns k = 8l..8l+7

  const float4* er = reinterpret_cast<const float4*>(emb + (size_t)i * DD + l * 8);
  float4 v0 = er[0], v1 = er[1];
  float e[8] = {v0.x, v0.y, v0.z, v0.w, v1.x, v1.y, v1.z, v1.w};

  float esq = 0.f;
#pragma unroll
  for (int j = 0; j < 8; ++j) esq += e[j] * e[j];
#pragma unroll
  for (int o = 32; o > 0; o >>= 1) esq += __shfl_xor(esq, o);
  const float inv = rsqrtf(esq);

  // target-logit partials against column label[i] (fp32, scattered reads)
  const int c = label[i];
  float dot = 0.f, wsq = 0.f;
#pragma unroll
  for (int j = 0; j < 8; ++j) {
    float w = kern[(size_t)(l * 8 + j) * CC + c];
    dot += e[j] * w;
    wsq += w * w;
  }
#pragma unroll
  for (int o = 32; o > 0; o >>= 1) {
    dot += __shfl_xor(dot, o);
    wsq += __shfl_xor(wsq, o);
  }

  // normalized bf16, 16B store at swizzled position
  unsigned int pk[4];
#pragma unroll
  for (int j = 0; j < 4; ++j) {
    unsigned int lo = f2bf(e[2 * j] * inv);
    unsigned int hi = f2bf(e[2 * j + 1] * inv);
    pk[j] = lo | (hi << 16);
  }
  const int kb = l >> 2;  // k-block (32 wide)
  const int off = kb * 32768 + i * 64 + ((16 * (l & 3)) ^ ((i & 3) << 4));
  uint4 v; v.x = pk[0]; v.y = pk[1]; v.z = pk[2]; v.w = pk[3];
  *reinterpret_cast<uint4*>(reinterpret_cast<char*>(wsA) + off) = v;

  if (l == 0) {
    float t = dot * rsqrtf(fmaxf(esq * wsq, 1e-30f));
    t = fminf(fmaxf(t, -1.f), 1.f);
    float st = sqrtf(fmaxf(0.f, 1.f - t * t));
    float ctm = t * COS_M_C - st * SIN_M_C;
    ws_target[i] = t;
    ws_ctm[i] = ctm;
    ws_ft[i] = (t > THRESH_C) ? ctm : (t - MM_C);
  }
}

// ---------------------------------------------------------------------------
// Kernel 2: deterministic reduction of 512 target logits -> t_new
// ---------------------------------------------------------------------------
__global__ __launch_bounds__(64) void k2_tnew(const float* __restrict__ ws_target,
                                              const float* __restrict__ t_in,
                                              float* __restrict__ ws_tnew) {
  const int l = threadIdx.x;
  float s = 0.f;
#pragma unroll
  for (int j = 0; j < 8; ++j) s += ws_target[l * 8 + j];
#pragma unroll
  for (int o = 32; o > 0; o >>= 1) s += __shfl_xor(s, o);
  if (l == 0) ws_tnew[0] = 0.01f * (s * (1.0f / 512.0f)) + 0.99f * t_in[0];
}

// ---------------------------------------------------------------------------
// Kernel 3: the GEMM + epilogue. One workgroup per 64-column tile, BM=512
// (kernel matrix read exactly once from HBM). 8 waves x (64 rows x 64 cols).
// A staged via global_load_lds (pre-swizzled in ws); B converted fp32->bf16
// in-register and ds_write'd transposed [n][k] with matching XOR swizzle.
// Column sumsq accumulated during staging -> epilogue normalization.
// ---------------------------------------------------------------------------
__global__ __launch_bounds__(512, 4) void k3_gemm(
    const float* __restrict__ kern, const unsigned short* __restrict__ wsA,
    const int* __restrict__ label, const float* __restrict__ ws_ctm,
    const float* __restrict__ ws_ft, const float* __restrict__ ws_tnew,
    float* __restrict__ out) {
  __shared__ __align__(16) unsigned short Alds[512 * 32];  // 32 KB [m][k] swz
  __shared__ __align__(16) unsigned short Blds[64 * 32];   // 4 KB  [n][k] swz
  __shared__ float colsq[64];

  const int t = threadIdx.x;
  const int l = t & 63;
  const int wv = t >> 6;  // wave 0..7
  const int n0 = blockIdx.x * 64;

  if (t < 64) colsq[t] = 0.f;

  const int bn = l;  // staging column
  const int gcol = n0 + bn;
  const bool colok = gcol < CC;
  const float* bcol = kern + gcol;

  float sumsq = 0.f;

  f32x4 acc[4][4];
#pragma unroll
  for (int a = 0; a < 4; ++a)
#pragma unroll
    for (int b = 0; b < 4; ++b) acc[a][b] = (f32x4){0.f, 0.f, 0.f, 0.f};

  const int lr = l & 15;
  const int lg = l >> 4;
  const int swz = (lg * 16) ^ ((lr & 3) << 4);
  const char* Ab = reinterpret_cast<const char*>(Alds);
  const char* Bb = reinterpret_cast<const char*>(Blds);

  for (int kt = 0; kt < 16; ++kt) {
    // ---- stage A: 32 KB linear copy (data pre-swizzled in ws) ----
    const char* gA = reinterpret_cast<const char*>(wsA) + kt * 32768;
#pragma unroll
    for (int i = 0; i < 4; ++i) {
      const int o = i * 8192 + t * 16;
      __builtin_amdgcn_global_load_lds(
          (const __attribute__((address_space(1))) unsigned int*)(gA + o),
          (__attribute__((address_space(3))) unsigned int*)(
              reinterpret_cast<char*>(Alds) + o),
          16, 0, 0);
    }
    // ---- stage B: wave wv loads k_local = 4wv..4wv+3 of its column ----
    const int kbase = kt * 32 + wv * 4;
    float bv0 = 0.f, bv1 = 0.f, bv2 = 0.f, bv3 = 0.f;
    if (colok) {
      const float* p = bcol + (size_t)kbase * CC;
      bv0 = p[0];
      bv1 = p[(size_t)CC];
      bv2 = p[(size_t)2 * CC];
      bv3 = p[(size_t)3 * CC];
    }
    sumsq += bv0 * bv0 + bv1 * bv1 + bv2 * bv2 + bv3 * bv3;
    uint2 pkd;
    pkd.x = (unsigned int)f2bf(bv0) | ((unsigned int)f2bf(bv1) << 16);
    pkd.y = (unsigned int)f2bf(bv2) | ((unsigned int)f2bf(bv3) << 16);
    const int wb = bn * 64 + ((wv * 8) ^ ((bn & 3) << 4));
    *reinterpret_cast<uint2*>(reinterpret_cast<char*>(Blds) + wb) = pkd;

    __syncthreads();  // drains vmcnt (global_load_lds) + lgkm

    short8 af[4], bfr[4];
#pragma unroll
    for (int mf = 0; mf < 4; ++mf) {
      const int m = wv * 64 + mf * 16 + lr;
      af[mf] = *reinterpret_cast<const short8*>(Ab + m * 64 + swz);
    }
#pragma unroll
    for (int nf = 0; nf < 4; ++nf) {
      const int n = nf * 16 + lr;
      bfr[nf] = *reinterpret_cast<const short8*>(Bb + n * 64 + swz);
    }
#pragma unroll
    for (int mf = 0; mf < 4; ++mf)
#pragma unroll
      for (int nf = 0; nf < 4; ++nf)
        acc[mf][nf] = __builtin_amdgcn_mfma_f32_16x16x32_bf16(
            af[mf], bfr[nf], acc[mf][nf], 0, 0, 0);

    __syncthreads();
  }

  // ---- column norm reduce (8 waves contribute per column) ----
  atomicAdd(&colsq[bn], sumsq);
  __syncthreads();

  const float tnew = ws_tnew[0];
  float invn[4];
#pragma unroll
  for (int nf = 0; nf < 4; ++nf)
    invn[nf] = rsqrtf(fmaxf(colsq[nf * 16 + lr], 1e-30f));

#pragma unroll
  for (int mf = 0; mf < 4; ++mf) {
#pragma unroll
    for (int r = 0; r < 4; ++r) {
      const int m = wv * 64 + mf * 16 + lg * 4 + r;
      const float ctm = ws_ctm[m];
      const float ft = ws_ft[m];
      const int lab = label[m];
      float* orow = out + (size_t)m * CC;
#pragma unroll
      for (int nf = 0; nf < 4; ++nf) {
        const int ncol = n0 + nf * 16 + lr;
        if (ncol < CC) {
          float cosv = acc[mf][nf][r] * invn[nf];
          cosv = fminf(fmaxf(cosv, -1.f), 1.f);
          float val = (cosv > ctm) ? cosv * (tnew + cosv) : cosv;
          if (ncol == lab) val = ft;
          orow[ncol] = val * S_SCALE;
        }
      }
    }
  }
}

// ---------------------------------------------------------------------------
extern "C" void kernel_launch(void* const* d_in, const int* in_sizes, int n_in,
                              void* d_out, int out_size, void* d_ws,
                              size_t ws_size, hipStream_t stream) {
  (void)in_sizes; (void)n_in; (void)out_size; (void)ws_size;
  const float* emb = (const float*)d_in[0];
  const float* kern = (const float*)d_in[1];
  const int* label = (const int*)d_in[2];
  const float* t_in = (const float*)d_in[3];
  float* out = (float*)d_out;

  char* ws = (char*)d_ws;
  unsigned short* wsA = (unsigned short*)ws;              // 512*512*2 = 524288 B
  float* ws_target = (float*)(ws + 524288);               // 2048 B
  float* ws_ctm = (float*)(ws + 526336);                  // 2048 B
  float* ws_ft = (float*)(ws + 528384);                   // 2048 B
  float* ws_tnew = (float*)(ws + 530432);                 // 4 B

  k1_prep<<<512, 64, 0, stream>>>(emb, kern, label, wsA, ws_target, ws_ctm, ws_ft);
  k2_tnew<<<1, 64, 0, stream>>>(ws_target, t_in, ws_tnew);
  k3_gemm<<<(CC + 63) / 64, 512, 0, stream>>>(kern, wsA, label, ws_ctm, ws_ft,
                                              ws_tnew, out);
}

// Round 4
// 153.708 us; speedup vs baseline: 1.6181x; 1.6181x over previous
//
#include <hip/hip_runtime.h>

#define CC 100000
#define DD 512

#define S_SCALE 30.0f
#define COS_M_C 0.8775825618903728f
#define SIN_M_C 0.479425538604203f
#define THRESH_C (-0.8775825618903728f)
#define MM_C 0.2397127693021015f

typedef __attribute__((ext_vector_type(8))) short short8;
typedef __attribute__((ext_vector_type(4))) float f32x4;

static __device__ __forceinline__ unsigned short f2bf(float x) {
  unsigned int u = __float_as_uint(x);
  unsigned int r = (u + 0x7fffu + ((u >> 16) & 1u)) >> 16;
  return (unsigned short)r;
}

#define FENCE() __builtin_amdgcn_sched_barrier(0)

// ---------------------------------------------------------------------------
// Kernel 1: per embedding row i (one wave per row): normalize, bf16, store to
// wsA in k-tiled + XOR-swizzled layout; compute target logit/ctm/ft.
// ---------------------------------------------------------------------------
__global__ __launch_bounds__(64) void k1_prep(
    const float* __restrict__ emb, const float* __restrict__ kern,
    const int* __restrict__ label, unsigned short* __restrict__ wsA,
    float* __restrict__ ws_target, float* __restrict__ ws_ctm,
    float* __restrict__ ws_ft) {
  const int i = blockIdx.x;
  const int l = threadIdx.x;

  const float4* er = reinterpret_cast<const float4*>(emb + (size_t)i * DD + l * 8);
  float4 v0 = er[0], v1 = er[1];
  float e[8] = {v0.x, v0.y, v0.z, v0.w, v1.x, v1.y, v1.z, v1.w};

  float esq = 0.f;
#pragma unroll
  for (int j = 0; j < 8; ++j) esq += e[j] * e[j];
#pragma unroll
  for (int o = 32; o > 0; o >>= 1) esq += __shfl_xor(esq, o);
  const float inv = rsqrtf(esq);

  const int c = label[i];
  float dot = 0.f, wsq = 0.f;
#pragma unroll
  for (int j = 0; j < 8; ++j) {
    float w = kern[(size_t)(l * 8 + j) * CC + c];
    dot += e[j] * w;
    wsq += w * w;
  }
#pragma unroll
  for (int o = 32; o > 0; o >>= 1) {
    dot += __shfl_xor(dot, o);
    wsq += __shfl_xor(wsq, o);
  }

  unsigned int pk[4];
#pragma unroll
  for (int j = 0; j < 4; ++j) {
    unsigned int lo = f2bf(e[2 * j] * inv);
    unsigned int hi = f2bf(e[2 * j + 1] * inv);
    pk[j] = lo | (hi << 16);
  }
  const int kb = l >> 2;
  const int off = kb * 32768 + i * 64 + ((16 * (l & 3)) ^ ((i & 3) << 4));
  uint4 v; v.x = pk[0]; v.y = pk[1]; v.z = pk[2]; v.w = pk[3];
  *reinterpret_cast<uint4*>(reinterpret_cast<char*>(wsA) + off) = v;

  if (l == 0) {
    float t = dot * rsqrtf(fmaxf(esq * wsq, 1e-30f));
    t = fminf(fmaxf(t, -1.f), 1.f);
    float st = sqrtf(fmaxf(0.f, 1.f - t * t));
    float ctm = t * COS_M_C - st * SIN_M_C;
    ws_target[i] = t;
    ws_ctm[i] = ctm;
    ws_ft[i] = (t > THRESH_C) ? ctm : (t - MM_C);
  }
}

// ---------------------------------------------------------------------------
// Kernel 2: deterministic reduction of 512 target logits -> t_new
// ---------------------------------------------------------------------------
__global__ __launch_bounds__(64) void k2_tnew(const float* __restrict__ ws_target,
                                              const float* __restrict__ t_in,
                                              float* __restrict__ ws_tnew) {
  const int l = threadIdx.x;
  float s = 0.f;
#pragma unroll
  for (int j = 0; j < 8; ++j) s += ws_target[l * 8 + j];
#pragma unroll
  for (int o = 32; o > 0; o >>= 1) s += __shfl_xor(s, o);
  if (l == 0) ws_tnew[0] = 0.01f * (s * (1.0f / 512.0f)) + 0.99f * t_in[0];
}

// ---------------------------------------------------------------------------
// Kernel 3: 512x64 tile GEMM + epilogue. Double-buffered A (gll) and B,
// counted vmcnt pipeline.  B double-buffer stride is 4096 BYTES
// (64 cols x 32 k x 2B) — the round-2/3 failure was stride 8192, which sent
// odd-parity B tiles out of the LDS allocation (reads returned 0).
// ---------------------------------------------------------------------------
__global__ __launch_bounds__(512, 4) void k3_gemm(
    const float* __restrict__ kern, const unsigned short* __restrict__ wsA,
    const int* __restrict__ label, const float* __restrict__ ws_ctm,
    const float* __restrict__ ws_ft, const float* __restrict__ ws_tnew,
    float* __restrict__ out) {
  __shared__ __align__(16) unsigned short Alds[2][512 * 32];  // 2x32768 B
  __shared__ __align__(16) unsigned short Blds[2][64 * 32];   // 2x4096 B
  __shared__ float colsq[64];

  const int t = threadIdx.x;
  const int l = t & 63;
  const int wv = t >> 6;
  const int n0 = blockIdx.x * 64;

  if (t < 64) colsq[t] = 0.f;

  const int bn = l;
  const int gcol = n0 + bn;
  const bool colok = gcol < CC;
  const float* bcol = kern + gcol;

  float sumsq = 0.f;

  f32x4 acc[4][4];
#pragma unroll
  for (int a = 0; a < 4; ++a)
#pragma unroll
    for (int b = 0; b < 4; ++b) acc[a][b] = (f32x4){0.f, 0.f, 0.f, 0.f};

  const int lr = l & 15;
  const int lg = l >> 4;
  const int swz = (lg * 16) ^ ((lr & 3) << 4);
  char* Ab = reinterpret_cast<char*>(Alds);
  char* Bb = reinterpret_cast<char*>(Blds);

#define BLOAD(KT, r0, r1, r2, r3)                                        \
  {                                                                      \
    if (colok) {                                                         \
      const float* p_ = bcol + (size_t)((KT) * 32 + wv * 4) * CC;        \
      r0 = p_[0];                                                        \
      r1 = p_[(size_t)CC];                                               \
      r2 = p_[(size_t)2 * CC];                                           \
      r3 = p_[(size_t)3 * CC];                                           \
    } else {                                                             \
      r0 = r1 = r2 = r3 = 0.f;                                           \
    }                                                                    \
  }

#define AGLL(KT)                                                         \
  {                                                                      \
    const char* gA_ = reinterpret_cast<const char*>(wsA) + (KT) * 32768; \
    char* lA_ = Ab + ((KT)&1) * 32768;                                   \
    _Pragma("unroll") for (int i_ = 0; i_ < 4; ++i_) {                   \
      const int o_ = i_ * 8192 + t * 16;                                 \
      __builtin_amdgcn_global_load_lds(                                  \
          (const __attribute__((address_space(1))) unsigned int*)(gA_ + o_), \
          (__attribute__((address_space(3))) unsigned int*)(lA_ + o_),   \
          16, 0, 0);                                                     \
    }                                                                    \
  }

#define BWRITE(KT, r0, r1, r2, r3)                                       \
  {                                                                      \
    sumsq += r0 * r0 + r1 * r1 + r2 * r2 + r3 * r3;                      \
    uint2 pk_;                                                           \
    pk_.x = (unsigned int)f2bf(r0) | ((unsigned int)f2bf(r1) << 16);     \
    pk_.y = (unsigned int)f2bf(r2) | ((unsigned int)f2bf(r3) << 16);     \
    *reinterpret_cast<uint2*>(Bb + ((KT)&1) * 4096 + bn * 64 +           \
                              ((wv * 8) ^ ((bn & 3) << 4))) = pk_;       \
  }

  // ---- prologue: tiles 0 and 1 in flight, tile 0 committed to LDS ----
  float c0, c1, c2, c3;  // B(0)
  float p0, p1, p2, p3;  // B(kt+1), loop-carried
  BLOAD(0, c0, c1, c2, c3);
  FENCE();
  AGLL(0);
  FENCE();
  BLOAD(1, p0, p1, p2, p3);
  FENCE();
  AGLL(1);
  FENCE();
  BWRITE(0, c0, c1, c2, c3);  // compiler inserts vmcnt for c*
  FENCE();
  asm volatile("s_waitcnt vmcnt(8)" ::: "memory");  // A(0) landed
  asm volatile("s_waitcnt lgkmcnt(0)" ::: "memory");
  FENCE();
  __builtin_amdgcn_s_barrier();
  FENCE();

  for (int kt = 0; kt < 16; ++kt) {
    const int cur = kt & 1;
    // fragment reads from current buffers
    short8 af[4], bfr[4];
#pragma unroll
    for (int mf = 0; mf < 4; ++mf) {
      const int m = wv * 64 + mf * 16 + lr;
      af[mf] = *reinterpret_cast<const short8*>(Ab + cur * 32768 + m * 64 + swz);
    }
#pragma unroll
    for (int nf = 0; nf < 4; ++nf) {
      const int n = nf * 16 + lr;
      bfr[nf] = *reinterpret_cast<const short8*>(Bb + cur * 4096 + n * 64 + swz);
    }
    // commit B(kt+1) to the idle buffer (its regs arrived; A(kt+1) may fly on)
    if (kt < 15) {
      asm volatile("s_waitcnt vmcnt(4)" ::: "memory");
      BWRITE(kt + 1, p0, p1, p2, p3);
    }
    __builtin_amdgcn_s_setprio(1);
#pragma unroll
    for (int mf = 0; mf < 4; ++mf)
#pragma unroll
      for (int nf = 0; nf < 4; ++nf)
        acc[mf][nf] = __builtin_amdgcn_mfma_f32_16x16x32_bf16(
            af[mf], bfr[nf], acc[mf][nf], 0, 0, 0);
    __builtin_amdgcn_s_setprio(0);
    asm volatile("s_waitcnt lgkmcnt(0)" ::: "memory");
    FENCE();
    __builtin_amdgcn_s_barrier();  // all waves done reading bufs[cur]
    FENCE();
    // issue tile kt+2 (B regs first, then A gll) and release A(kt+1)
    if (kt < 14) {
      BLOAD(kt + 2, p0, p1, p2, p3);
      FENCE();
      AGLL(kt + 2);
      FENCE();
      asm volatile("s_waitcnt vmcnt(8)" ::: "memory");  // A(kt+1) landed
    } else {
      asm volatile("s_waitcnt vmcnt(0)" ::: "memory");
    }
    FENCE();
    __builtin_amdgcn_s_barrier();
    FENCE();
  }

  // ---- column-norm reduce ----
  atomicAdd(&colsq[bn], sumsq);
  asm volatile("s_waitcnt lgkmcnt(0)" ::: "memory");
  FENCE();
  __builtin_amdgcn_s_barrier();
  FENCE();

  const float tnew = ws_tnew[0];
  float invn[4];
#pragma unroll
  for (int nf = 0; nf < 4; ++nf)
    invn[nf] = rsqrtf(fmaxf(colsq[nf * 16 + lr], 1e-30f));

  // ---- epilogue: transpose through wave-private LDS, float4 stores ----
  float* est = reinterpret_cast<float*>(Alds) + (size_t)wv * 1088;  // 16x68
  const int c4 = n0 + lr * 4;
#pragma unroll
  for (int mf = 0; mf < 4; ++mf) {
    asm volatile("s_waitcnt lgkmcnt(0)" ::: "memory");  // WAR vs prev reads
    FENCE();
#pragma unroll
    for (int r = 0; r < 4; ++r)
#pragma unroll
      for (int nf = 0; nf < 4; ++nf)
        est[(lg * 4 + r) * 68 + nf * 16 + lr] = acc[mf][nf][r] * invn[nf];
    asm volatile("s_waitcnt lgkmcnt(0)" ::: "memory");  // RAW: writes visible
    FENCE();
#pragma unroll
    for (int p = 0; p < 4; ++p) {
      const int rr = p * 4 + lg;
      const int m = wv * 64 + mf * 16 + rr;
      const float ctm = ws_ctm[m];
      const float ft = ws_ft[m];
      const int lab = label[m];
      float4 vv = *reinterpret_cast<const float4*>(&est[rr * 68 + lr * 4]);
      if (c4 < CC) {
        float ov[4] = {vv.x, vv.y, vv.z, vv.w};
#pragma unroll
        for (int j = 0; j < 4; ++j) {
          float cosv = fminf(fmaxf(ov[j], -1.f), 1.f);
          float val = (cosv > ctm) ? cosv * (tnew + cosv) : cosv;
          if (c4 + j == lab) val = ft;
          ov[j] = val * S_SCALE;
        }
        float4 st4;
        st4.x = ov[0]; st4.y = ov[1]; st4.z = ov[2]; st4.w = ov[3];
        *reinterpret_cast<float4*>(out + (size_t)m * CC + c4) = st4;
      }
    }
  }
#undef BLOAD
#undef AGLL
#undef BWRITE
}

// ---------------------------------------------------------------------------
extern "C" void kernel_launch(void* const* d_in, const int* in_sizes, int n_in,
                              void* d_out, int out_size, void* d_ws,
                              size_t ws_size, hipStream_t stream) {
  (void)in_sizes; (void)n_in; (void)out_size; (void)ws_size;
  const float* emb = (const float*)d_in[0];
  const float* kern = (const float*)d_in[1];
  const int* label = (const int*)d_in[2];
  const float* t_in = (const float*)d_in[3];
  float* out = (float*)d_out;

  char* ws = (char*)d_ws;
  unsigned short* wsA = (unsigned short*)ws;
  float* ws_target = (float*)(ws + 524288);
  float* ws_ctm = (float*)(ws + 526336);
  float* ws_ft = (float*)(ws + 528384);
  float* ws_tnew = (float*)(ws + 530432);

  k1_prep<<<512, 64, 0, stream>>>(emb, kern, label, wsA, ws_target, ws_ctm, ws_ft);
  k2_tnew<<<1, 64, 0, stream>>>(ws_target, t_in, ws_tnew);
  k3_gemm<<<(CC + 63) / 64, 512, 0, stream>>>(kern, wsA, label, ws_ctm, ws_ft,
                                              ws_tnew, out);
}